// Round 1
// baseline (370.603 us; speedup 1.0000x reference)
//
#include <hip/hip_runtime.h>
#include <cstddef>
#include <cstdint>

#define EPSF 1e-8f

static constexpr int Bn = 128;
static constexpr int Nn = 2048;
static constexpr int Kn = 256;
static constexpr int TPB = 256;
static constexpr int ROWS_PER_BLOCK = 64;           // 16 rows per wave
static constexpr int CHUNKS = Nn / ROWS_PER_BLOCK;  // 32

// Kernel 1: z[b,n] = beta[b] * dot(keys[b,n,:], k[b,:]) / (||keys[b,n,:]|| * ||k[b,:]||)
// Wave layout: 16 lanes per row (4 rows in flight per wave), fully-coalesced float4 loads,
// 4-stage shfl_xor reduction within 16-lane groups (2 DS-ops per row).
__global__ __launch_bounds__(TPB) void score_kernel(
    const float* __restrict__ q,
    const float* __restrict__ beta,
    const float* __restrict__ keys,
    float* __restrict__ z)
{
    const int b     = blockIdx.x / CHUNKS;
    const int chunk = blockIdx.x % CHUNKS;
    const int wv    = threadIdx.x >> 6;
    const int lane  = threadIdx.x & 63;
    const int sub   = lane >> 4;   // row within 4-row tile
    const int c     = lane & 15;   // column sub-lane (16 lanes cover K=256 as 4 float4 each)

    // query fragments for this lane's columns: cols 4*c + 64*i, i = 0..3
    const float4* qf4 = (const float4*)(q + (size_t)b * Kn);
    const float4 kq0 = qf4[c +  0];
    const float4 kq1 = qf4[c + 16];
    const float4 kq2 = qf4[c + 32];
    const float4 kq3 = qf4[c + 48];

    float qs = kq0.x*kq0.x + kq0.y*kq0.y + kq0.z*kq0.z + kq0.w*kq0.w
             + kq1.x*kq1.x + kq1.y*kq1.y + kq1.z*kq1.z + kq1.w*kq1.w
             + kq2.x*kq2.x + kq2.y*kq2.y + kq2.z*kq2.z + kq2.w*kq2.w
             + kq3.x*kq3.x + kq3.y*kq3.y + kq3.z*kq3.z + kq3.w*kq3.w;
    qs += __shfl_xor(qs, 8);
    qs += __shfl_xor(qs, 4);
    qs += __shfl_xor(qs, 2);
    qs += __shfl_xor(qs, 1);
    const float qn = fmaxf(sqrtf(qs), EPSF);
    const float scale0 = beta[b] / qn;

    const int rbase = chunk * ROWS_PER_BLOCK + wv * 16;
    #pragma unroll
    for (int tt = 0; tt < 4; ++tt) {
        const int row = rbase + tt * 4 + sub;
        const float4* rp = (const float4*)(keys + ((size_t)b * Nn + row) * Kn);
        const float4 v0 = rp[c +  0];
        const float4 v1 = rp[c + 16];
        const float4 v2 = rp[c + 32];
        const float4 v3 = rp[c + 48];
        float d = v0.x*kq0.x + v0.y*kq0.y + v0.z*kq0.z + v0.w*kq0.w
                + v1.x*kq1.x + v1.y*kq1.y + v1.z*kq1.z + v1.w*kq1.w
                + v2.x*kq2.x + v2.y*kq2.y + v2.z*kq2.z + v2.w*kq2.w
                + v3.x*kq3.x + v3.y*kq3.y + v3.z*kq3.z + v3.w*kq3.w;
        float s = v0.x*v0.x + v0.y*v0.y + v0.z*v0.z + v0.w*v0.w
                + v1.x*v1.x + v1.y*v1.y + v1.z*v1.z + v1.w*v1.w
                + v2.x*v2.x + v2.y*v2.y + v2.z*v2.z + v2.w*v2.w
                + v3.x*v3.x + v3.y*v3.y + v3.z*v3.z + v3.w*v3.w;
        d += __shfl_xor(d, 8);  s += __shfl_xor(s, 8);
        d += __shfl_xor(d, 4);  s += __shfl_xor(s, 4);
        d += __shfl_xor(d, 2);  s += __shfl_xor(s, 2);
        d += __shfl_xor(d, 1);  s += __shfl_xor(s, 1);
        if (c == 0) {
            z[(size_t)b * Nn + row] = d * scale0 / fmaxf(sqrtf(s), EPSF);
        }
    }
}

// Kernel 2: per batch row of z [N=2048]: exact top-C selection + sharpen + normalize.
// w_i = (e_i * mask_i)^g / sum_j (e_j * mask_j)^g  with e_i = exp(z_i - max) — both
// reference normalizations cancel algebraically.
__global__ __launch_bounds__(TPB) void topk_kernel(
    const float* __restrict__ z,
    const float* __restrict__ gamma,
    const int* __restrict__ cand,
    float* __restrict__ out)
{
    const int b    = blockIdx.x;
    const int tid  = threadIdx.x;
    const int lane = tid & 63;
    const int wv   = tid >> 6;
    const int C    = cand[0];

    __shared__ float    fred[4];
    __shared__ int      ired[4];
    __shared__ unsigned sscan[TPB];

    // thread owns elements tid*8 .. tid*8+7 (index order, needed for tie-breaking)
    float v[8];
    {
        const float4* zp = (const float4*)(z + (size_t)b * Nn) + (size_t)tid * 2;
        const float4 a0 = zp[0];
        const float4 a1 = zp[1];
        v[0]=a0.x; v[1]=a0.y; v[2]=a0.z; v[3]=a0.w;
        v[4]=a1.x; v[5]=a1.y; v[6]=a1.z; v[7]=a1.w;
    }

    // monotonic uint mapping of float
    unsigned key[8];
    #pragma unroll
    for (int j = 0; j < 8; ++j) {
        const unsigned u = __float_as_uint(v[j]);
        key[j] = (u & 0x80000000u) ? ~u : (u | 0x80000000u);
    }

    // block max (for exp stability; exact value not required mathematically)
    float mx = v[0];
    #pragma unroll
    for (int j = 1; j < 8; ++j) mx = fmaxf(mx, v[j]);
    #pragma unroll
    for (int off = 32; off >= 1; off >>= 1) mx = fmaxf(mx, __shfl_xor(mx, off));
    if (lane == 0) fred[wv] = mx;
    __syncthreads();
    mx = fmaxf(fmaxf(fred[0], fred[1]), fmaxf(fred[2], fred[3]));
    __syncthreads();

    // bitwise binary search: largest t with count(key >= t) >= C  ->  t = C-th largest
    unsigned t = 0u;
    for (int bit = 31; bit >= 0; --bit) {
        const unsigned ct = t | (1u << bit);
        int cnt = 0;
        #pragma unroll
        for (int j = 0; j < 8; ++j)
            cnt += (int)__popcll(__ballot(key[j] >= ct));
        if (lane == 0) ired[wv] = cnt;
        __syncthreads();
        cnt = ired[0] + ired[1] + ired[2] + ired[3];
        __syncthreads();
        if (cnt >= C) t = ct;
    }

    // strict-greater count -> how many tie slots remain
    int cgt = 0;
    #pragma unroll
    for (int j = 0; j < 8; ++j)
        cgt += (int)__popcll(__ballot(key[j] > t));
    if (lane == 0) ired[wv] = cgt;
    __syncthreads();
    cgt = ired[0] + ired[1] + ired[2] + ired[3];
    __syncthreads();
    const unsigned need = (unsigned)(C - cgt);   // >= 1 by maximality of t

    // tie ranks in global index order (exclusive prefix over threads via scan)
    unsigned tierank[8];
    unsigned myties = 0;
    #pragma unroll
    for (int j = 0; j < 8; ++j) { tierank[j] = myties; myties += (key[j] == t) ? 1u : 0u; }
    sscan[tid] = myties;
    __syncthreads();
    for (int off = 1; off < TPB; off <<= 1) {
        const unsigned x = (tid >= off) ? sscan[tid - off] : 0u;
        __syncthreads();
        sscan[tid] += x;
        __syncthreads();
    }
    const unsigned prefix = sscan[tid] - myties;

    const float g = gamma[b];
    const float tinyf = __powf(1e-16f, g);   // mask^g for non-selected (may underflow to 0 — matches ref)
    float a[8];
    float ssum = 0.f;
    #pragma unroll
    for (int j = 0; j < 8; ++j) {
        const bool sel = (key[j] > t) || ((key[j] == t) && ((prefix + tierank[j]) < need));
        a[j] = __expf(g * (v[j] - mx)) * (sel ? 1.0f : tinyf);
        ssum += a[j];
    }
    #pragma unroll
    for (int off = 32; off >= 1; off >>= 1) ssum += __shfl_xor(ssum, off);
    if (lane == 0) fred[wv] = ssum;
    __syncthreads();
    ssum = fred[0] + fred[1] + fred[2] + fred[3];

    const float inv = 1.0f / ssum;           // ssum >= 1 (max element contributes exp(0)=1)
    const float4 o0 = make_float4(a[0]*inv, a[1]*inv, a[2]*inv, a[3]*inv);
    const float4 o1 = make_float4(a[4]*inv, a[5]*inv, a[6]*inv, a[7]*inv);
    float4* op = (float4*)(out + (size_t)b * Nn) + (size_t)tid * 2;
    op[0] = o0;
    op[1] = o1;
}

extern "C" void kernel_launch(void* const* d_in, const int* in_sizes, int n_in,
                              void* d_out, int out_size, void* d_ws, size_t ws_size,
                              hipStream_t stream) {
    const float* q     = (const float*)d_in[0];   // k      [B,K]
    const float* beta  = (const float*)d_in[1];   // beta   [B,1]
    const float* gamma = (const float*)d_in[2];   // gamma  [B,1]
    const float* keys  = (const float*)d_in[3];   // keys   [B,N,K]
    const int*   cand  = (const int*)d_in[4];     // candidates (scalar)
    float* out = (float*)d_out;                   // w      [B,N]
    float* z   = (float*)d_ws;                    // scratch [B,N] floats = 1 MiB

    score_kernel<<<dim3(Bn * CHUNKS), dim3(TPB), 0, stream>>>(q, beta, keys, z);
    topk_kernel<<<dim3(Bn), dim3(TPB), 0, stream>>>(z, gamma, cand, out);
}

// Round 3
// 348.137 us; speedup vs baseline: 1.0645x; 1.0645x over previous
//
#include <hip/hip_runtime.h>
#include <cstddef>
#include <cstdint>

#define EPSF 1e-8f

typedef float vf4 __attribute__((ext_vector_type(4)));

static constexpr int Bn = 128;
static constexpr int Nn = 2048;
static constexpr int Kn = 256;
static constexpr int TPB = 256;
static constexpr int ROWS_PER_BLOCK = 64;           // 16 rows per wave (2 iters x 8 rows)
static constexpr int CHUNKS = Nn / ROWS_PER_BLOCK;  // 32
static constexpr int MAXC = 64;                      // candidate buffer sized for C <= 64 (actual C = 32)

// Kernel 1: z[b,n] = beta[b] * dot(keys[b,n,:], k[b,:]) / (||keys[b,n,:]|| * ||k[b,:]||)
// 8 lanes per row (8 rows in flight per wave): 3-stage shfl reduction = 6 DS ops/row.
// Nontemporal vf4 loads for the 256 MiB keys stream. 4-way split accumulators keep
// the dependent FMA chain at 8.
__global__ __launch_bounds__(TPB) void score_kernel(
    const float* __restrict__ q,
    const float* __restrict__ beta,
    const float* __restrict__ keys,
    float* __restrict__ z)
{
    const int b     = blockIdx.x / CHUNKS;
    const int chunk = blockIdx.x % CHUNKS;
    const int wv    = threadIdx.x >> 6;
    const int lane  = threadIdx.x & 63;
    const int g     = lane >> 3;   // row group 0..7
    const int c     = lane & 7;    // column sub-lane: 8 lanes x 8 vf4 cover K=256

    const vf4* qf4 = (const vf4*)(q + (size_t)b * Kn);
    vf4 kq[8];
    #pragma unroll
    for (int i = 0; i < 8; ++i) kq[i] = qf4[c + 8 * i];

    float qa[4] = {0.f, 0.f, 0.f, 0.f};
    #pragma unroll
    for (int i = 0; i < 8; ++i) {
        const vf4 kk = kq[i];
        qa[i & 3] = fmaf(kk[0], kk[0], fmaf(kk[1], kk[1], fmaf(kk[2], kk[2], fmaf(kk[3], kk[3], qa[i & 3]))));
    }
    float qs = (qa[0] + qa[1]) + (qa[2] + qa[3]);
    qs += __shfl_xor(qs, 4);
    qs += __shfl_xor(qs, 2);
    qs += __shfl_xor(qs, 1);
    const float scale0 = beta[b] / fmaxf(sqrtf(qs), EPSF);

    const int rbase = chunk * ROWS_PER_BLOCK + wv * 16 + g;
    #pragma unroll
    for (int it = 0; it < 2; ++it) {
        const int row = rbase + it * 8;
        const vf4* rp = (const vf4*)(keys + ((size_t)b * Nn + row) * Kn);
        vf4 v[8];
        #pragma unroll
        for (int i = 0; i < 8; ++i) v[i] = __builtin_nontemporal_load(&rp[c + 8 * i]);
        float d[4] = {0.f, 0.f, 0.f, 0.f};
        float s[4] = {0.f, 0.f, 0.f, 0.f};
        #pragma unroll
        for (int i = 0; i < 8; ++i) {
            const vf4 vv = v[i];
            const vf4 kk = kq[i];
            d[i & 3] = fmaf(vv[0], kk[0], fmaf(vv[1], kk[1], fmaf(vv[2], kk[2], fmaf(vv[3], kk[3], d[i & 3]))));
            s[i & 3] = fmaf(vv[0], vv[0], fmaf(vv[1], vv[1], fmaf(vv[2], vv[2], fmaf(vv[3], vv[3], s[i & 3]))));
        }
        float dd = (d[0] + d[1]) + (d[2] + d[3]);
        float ss = (s[0] + s[1]) + (s[2] + s[3]);
        dd += __shfl_xor(dd, 4);  ss += __shfl_xor(ss, 4);
        dd += __shfl_xor(dd, 2);  ss += __shfl_xor(ss, 2);
        dd += __shfl_xor(dd, 1);  ss += __shfl_xor(ss, 1);
        if (c == 0) {
            z[(size_t)b * Nn + row] = dd * scale0 / fmaxf(sqrtf(ss), EPSF);
        }
    }
}

// Kernel 2: exact top-C select + sharpen + normalize, one block per batch row.
// w_i = (e_i * mask_i)^g / sum, e_i = exp(z_i - off) — both reference normalizations
// cancel; the offset cancels too, so we use the threshold value (no max reduction).
// Barrier-light: per-wave ballot binary search (no barriers) -> 4C candidates in LDS
// -> wave-0 ballot search -> one packed wave shfl-scan for gt/eq counts. ~4 barriers.
__global__ __launch_bounds__(TPB) void topk_kernel(
    const float* __restrict__ z,
    const float* __restrict__ gamma,
    const int* __restrict__ cand,
    float* __restrict__ out)
{
    const int b    = blockIdx.x;
    const int tid  = threadIdx.x;
    const int lane = tid & 63;
    const int wv   = tid >> 6;
    const int C    = cand[0];   // 32

    __shared__ unsigned cbuf[4 * MAXC];  // per-wave top-C candidate values
    __shared__ unsigned spack[4];        // per-wave (gt<<16 | eq) totals
    __shared__ unsigned st;              // global threshold key
    __shared__ float    fred[4];

    // thread owns elements tid*8 .. tid*8+7 (global index order — required for tie-breaking)
    float v[8];
    {
        const vf4* zp = (const vf4*)(z + (size_t)b * Nn) + (size_t)tid * 2;
        const vf4 a0 = zp[0];
        const vf4 a1 = zp[1];
        v[0]=a0[0]; v[1]=a0[1]; v[2]=a0[2]; v[3]=a0[3];
        v[4]=a1[0]; v[5]=a1[1]; v[6]=a1[2]; v[7]=a1[3];
    }

    unsigned key[8];
    #pragma unroll
    for (int j = 0; j < 8; ++j) {
        const unsigned u = __float_as_uint(v[j]);
        key[j] = (u & 0x80000000u) ? ~u : (u | 0x80000000u);
    }

    // per-wave C-th-largest among this wave's 512 keys (wave-synchronous, no barriers)
    unsigned tw = 0u;
    for (int bit = 31; bit >= 0; --bit) {
        const unsigned ct = tw | (1u << bit);
        int cnt = 0;
        #pragma unroll
        for (int j = 0; j < 8; ++j)
            cnt += (int)__popcll(__ballot(key[j] >= ct));
        if (cnt >= C) tw = ct;
    }

    // emit wave's top-C multiset: all keys > tw (count < C), pad with copies of tw.
    // slots via ballot prefix — no atomics.
    {
        const unsigned long long below_mask = (1ull << lane) - 1ull;
        int base = 0;
        #pragma unroll
        for (int j = 0; j < 8; ++j) {
            const unsigned long long m = __ballot(key[j] > tw);
            if (key[j] > tw) {
                const int slot = base + (int)__popcll(m & below_mask);
                cbuf[wv * MAXC + slot] = key[j];
            }
            base += (int)__popcll(m);
        }
        for (int i = base + lane; i < C; i += 64) cbuf[wv * MAXC + i] = tw;
    }
    __syncthreads();

    // wave 0: C-th largest of the 4C candidates == global C-th largest key
    if (wv == 0) {
        unsigned cv[4];
        #pragma unroll
        for (int j = 0; j < 4; ++j) {
            const int idx = lane + 64 * j;
            const int w2 = idx / MAXC, i2 = idx % MAXC;      // MAXC=64: w2=j at lane span
            cv[j] = (i2 < C) ? cbuf[w2 * MAXC + i2] : 0u;    // pad 0 never passes ct>=1
        }
        unsigned t = 0u;
        for (int bit = 31; bit >= 0; --bit) {
            const unsigned ct = t | (1u << bit);
            int cnt = 0;
            #pragma unroll
            for (int j = 0; j < 4; ++j)
                cnt += (int)__popcll(__ballot(cv[j] >= ct));
            if (cnt >= C) t = ct;
        }
        if (lane == 0) st = t;
    }
    __syncthreads();
    const unsigned t = st;

    // global recount: gt/eq packed scan in index order (wave shfl-scan + LDS combine)
    int gt = 0, eq = 0;
    #pragma unroll
    for (int j = 0; j < 8; ++j) { gt += (key[j] > t); eq += (key[j] == t); }
    const unsigned p = ((unsigned)gt << 16) | (unsigned)eq;
    unsigned x = p;
    #pragma unroll
    for (int off = 1; off < 64; off <<= 1) {
        const unsigned y = __shfl_up(x, off);
        if (lane >= off) x += y;
    }
    if (lane == 63) spack[wv] = x;   // wave inclusive total
    __syncthreads();
    unsigned base = 0, total = 0;
    #pragma unroll
    for (int w2 = 0; w2 < 4; ++w2) {
        const unsigned sv = spack[w2];
        total += sv;
        if (w2 < wv) base += sv;
    }
    const unsigned excl = base + x - p;             // exclusive prefix before my elements
    const int cgt_total = (int)(total >> 16);
    const int need      = C - cgt_total;            // >= 1 by maximality of t
    const int eq_before = (int)(excl & 0xFFFFu);

    // threshold value as exp offset: selected z - tval >= 0, bounded by beta*2 ~ 11; g*11 <= 33 -> fp32-safe
    const float tval = __uint_as_float((t & 0x80000000u) ? (t ^ 0x80000000u) : ~t);
    const float g = gamma[b];
    const float tiny = __powf(1e-16f, g);           // may underflow to 0 — matches ref
    float a[8];
    float ssum = 0.f;
    int eqseen = 0;
    #pragma unroll
    for (int j = 0; j < 8; ++j) {
        const bool sel = (key[j] > t) || ((key[j] == t) && ((eq_before + eqseen) < need));
        eqseen += (key[j] == t);
        a[j] = __expf(g * (v[j] - tval)) * (sel ? 1.0f : tiny);
        ssum += a[j];
    }
    #pragma unroll
    for (int off = 32; off >= 1; off >>= 1) ssum += __shfl_xor(ssum, off);
    if (lane == 0) fred[wv] = ssum;
    __syncthreads();
    const float tot = (fred[0] + fred[1]) + (fred[2] + fred[3]);
    const float inv = 1.0f / tot;

    vf4 o0, o1;
    o0[0]=a[0]*inv; o0[1]=a[1]*inv; o0[2]=a[2]*inv; o0[3]=a[3]*inv;
    o1[0]=a[4]*inv; o1[1]=a[5]*inv; o1[2]=a[6]*inv; o1[3]=a[7]*inv;
    vf4* op = (vf4*)(out + (size_t)b * Nn) + (size_t)tid * 2;
    op[0] = o0;
    op[1] = o1;
}

extern "C" void kernel_launch(void* const* d_in, const int* in_sizes, int n_in,
                              void* d_out, int out_size, void* d_ws, size_t ws_size,
                              hipStream_t stream) {
    const float* q     = (const float*)d_in[0];   // k      [B,K]
    const float* beta  = (const float*)d_in[1];   // beta   [B,1]
    const float* gamma = (const float*)d_in[2];   // gamma  [B,1]
    const float* keys  = (const float*)d_in[3];   // keys   [B,N,K]
    const int*   cand  = (const int*)d_in[4];     // candidates (scalar)
    float* out = (float*)d_out;                   // w      [B,N]
    float* z   = (float*)d_ws;                    // scratch [B,N] floats = 1 MiB

    score_kernel<<<dim3(Bn * CHUNKS), dim3(TPB), 0, stream>>>(q, beta, keys, z);
    topk_kernel<<<dim3(Bn), dim3(TPB), 0, stream>>>(z, gamma, cand, out);
}

// Round 4
// 340.466 us; speedup vs baseline: 1.0885x; 1.0225x over previous
//
#include <hip/hip_runtime.h>
#include <cstddef>
#include <cstdint>

#define EPSF 1e-8f

typedef float vf4 __attribute__((ext_vector_type(4)));

static constexpr int Bn = 128;
static constexpr int Nn = 2048;
static constexpr int Kn = 256;
static constexpr int TPB = 256;
static constexpr int ROWS_PER_BLOCK = 64;           // 16 rows per wave (2 groups x 8 rows)
static constexpr int CHUNKS = Nn / ROWS_PER_BLOCK;  // 32
static constexpr int MAXC = 64;                      // candidate buffer sized for C <= 64 (actual C = 32)

// Kernel 1: z[b,n] = beta[b] * dot(keys[b,n,:], k[b,:]) / (||keys[b,n,:]|| * ||k[b,:]||)
// 8 lanes per row, 8 rows in flight per wave per group. ALL 16 nontemporal vf4 loads
// (two row-groups) issued up front per wave -> 16 outstanding vmem ops for latency
// hiding; the two FMA+shuffle drain chains run while the second batch is in flight.
__global__ __launch_bounds__(TPB) void score_kernel(
    const float* __restrict__ q,
    const float* __restrict__ beta,
    const float* __restrict__ keys,
    float* __restrict__ z)
{
    const int b     = blockIdx.x / CHUNKS;
    const int chunk = blockIdx.x % CHUNKS;
    const int wv    = threadIdx.x >> 6;
    const int lane  = threadIdx.x & 63;
    const int g     = lane >> 3;   // row group 0..7
    const int c     = lane & 7;    // column sub-lane: 8 lanes x 8 vf4 cover K=256

    const vf4* qf4 = (const vf4*)(q + (size_t)b * Kn);
    vf4 kq[8];
    #pragma unroll
    for (int i = 0; i < 8; ++i) kq[i] = qf4[c + 8 * i];

    const int row0 = chunk * ROWS_PER_BLOCK + wv * 16 + g;
    const vf4* rp0 = (const vf4*)(keys + ((size_t)b * Nn + row0) * Kn);
    const vf4* rp1 = (const vf4*)(keys + ((size_t)b * Nn + row0 + 8) * Kn);

    vf4 v0[8], v1[8];
    #pragma unroll
    for (int i = 0; i < 8; ++i) v0[i] = __builtin_nontemporal_load(&rp0[c + 8 * i]);
    #pragma unroll
    for (int i = 0; i < 8; ++i) v1[i] = __builtin_nontemporal_load(&rp1[c + 8 * i]);

    float qa[4] = {0.f, 0.f, 0.f, 0.f};
    #pragma unroll
    for (int i = 0; i < 8; ++i) {
        const vf4 kk = kq[i];
        qa[i & 3] = fmaf(kk[0], kk[0], fmaf(kk[1], kk[1], fmaf(kk[2], kk[2], fmaf(kk[3], kk[3], qa[i & 3]))));
    }
    float qs = (qa[0] + qa[1]) + (qa[2] + qa[3]);
    qs += __shfl_xor(qs, 4);
    qs += __shfl_xor(qs, 2);
    qs += __shfl_xor(qs, 1);
    const float scale0 = beta[b] / fmaxf(sqrtf(qs), EPSF);

    // drain group 0
    float d0[4] = {0.f,0.f,0.f,0.f}, s0[4] = {0.f,0.f,0.f,0.f};
    #pragma unroll
    for (int i = 0; i < 8; ++i) {
        const vf4 vv = v0[i];
        const vf4 kk = kq[i];
        d0[i & 3] = fmaf(vv[0], kk[0], fmaf(vv[1], kk[1], fmaf(vv[2], kk[2], fmaf(vv[3], kk[3], d0[i & 3]))));
        s0[i & 3] = fmaf(vv[0], vv[0], fmaf(vv[1], vv[1], fmaf(vv[2], vv[2], fmaf(vv[3], vv[3], s0[i & 3]))));
    }
    float dd0 = (d0[0] + d0[1]) + (d0[2] + d0[3]);
    float ss0 = (s0[0] + s0[1]) + (s0[2] + s0[3]);

    // drain group 1
    float d1[4] = {0.f,0.f,0.f,0.f}, s1[4] = {0.f,0.f,0.f,0.f};
    #pragma unroll
    for (int i = 0; i < 8; ++i) {
        const vf4 vv = v1[i];
        const vf4 kk = kq[i];
        d1[i & 3] = fmaf(vv[0], kk[0], fmaf(vv[1], kk[1], fmaf(vv[2], kk[2], fmaf(vv[3], kk[3], d1[i & 3]))));
        s1[i & 3] = fmaf(vv[0], vv[0], fmaf(vv[1], vv[1], fmaf(vv[2], vv[2], fmaf(vv[3], vv[3], s1[i & 3]))));
    }
    float dd1 = (d1[0] + d1[1]) + (d1[2] + d1[3]);
    float ss1 = (s1[0] + s1[1]) + (s1[2] + s1[3]);

    // interleaved shuffle reductions (independent chains overlap DS latency)
    dd0 += __shfl_xor(dd0, 4);  ss0 += __shfl_xor(ss0, 4);  dd1 += __shfl_xor(dd1, 4);  ss1 += __shfl_xor(ss1, 4);
    dd0 += __shfl_xor(dd0, 2);  ss0 += __shfl_xor(ss0, 2);  dd1 += __shfl_xor(dd1, 2);  ss1 += __shfl_xor(ss1, 2);
    dd0 += __shfl_xor(dd0, 1);  ss0 += __shfl_xor(ss0, 1);  dd1 += __shfl_xor(dd1, 1);  ss1 += __shfl_xor(ss1, 1);

    if (c == 0) {
        z[(size_t)b * Nn + row0]     = dd0 * scale0 / fmaxf(sqrtf(ss0), EPSF);
        z[(size_t)b * Nn + row0 + 8] = dd1 * scale0 / fmaxf(sqrtf(ss1), EPSF);
    }
}

// Kernel 2: exact top-C select + sharpen + normalize, one block per batch row.
// w_i = (e_i * mask_i)^g / sum, e_i = exp(z_i - off) — both reference normalizations
// cancel; the offset cancels too, so we use the threshold value (no max reduction).
__global__ __launch_bounds__(TPB) void topk_kernel(
    const float* __restrict__ z,
    const float* __restrict__ gamma,
    const int* __restrict__ cand,
    float* __restrict__ out)
{
    const int b    = blockIdx.x;
    const int tid  = threadIdx.x;
    const int lane = tid & 63;
    const int wv   = tid >> 6;
    const int C    = cand[0];   // 32

    __shared__ unsigned cbuf[4 * MAXC];  // per-wave top-C candidate values
    __shared__ unsigned spack[4];        // per-wave (gt<<16 | eq) totals
    __shared__ unsigned st;              // global threshold key
    __shared__ float    fred[4];

    // thread owns elements tid*8 .. tid*8+7 (global index order — required for tie-breaking)
    float v[8];
    {
        const vf4* zp = (const vf4*)(z + (size_t)b * Nn) + (size_t)tid * 2;
        const vf4 a0 = zp[0];
        const vf4 a1 = zp[1];
        v[0]=a0[0]; v[1]=a0[1]; v[2]=a0[2]; v[3]=a0[3];
        v[4]=a1[0]; v[5]=a1[1]; v[6]=a1[2]; v[7]=a1[3];
    }

    unsigned key[8];
    #pragma unroll
    for (int j = 0; j < 8; ++j) {
        const unsigned u = __float_as_uint(v[j]);
        key[j] = (u & 0x80000000u) ? ~u : (u | 0x80000000u);
    }

    // per-wave C-th-largest among this wave's 512 keys (wave-synchronous, no barriers)
    unsigned tw = 0u;
    for (int bit = 31; bit >= 0; --bit) {
        const unsigned ct = tw | (1u << bit);
        int cnt = 0;
        #pragma unroll
        for (int j = 0; j < 8; ++j)
            cnt += (int)__popcll(__ballot(key[j] >= ct));
        if (cnt >= C) tw = ct;
    }

    // emit wave's top-C multiset: all keys > tw (count < C), pad with copies of tw.
    {
        const unsigned long long below_mask = (1ull << lane) - 1ull;
        int base = 0;
        #pragma unroll
        for (int j = 0; j < 8; ++j) {
            const unsigned long long m = __ballot(key[j] > tw);
            if (key[j] > tw) {
                const int slot = base + (int)__popcll(m & below_mask);
                cbuf[wv * MAXC + slot] = key[j];
            }
            base += (int)__popcll(m);
        }
        for (int i = base + lane; i < C; i += 64) cbuf[wv * MAXC + i] = tw;
    }
    __syncthreads();

    // wave 0: C-th largest of the 4C candidates == global C-th largest key
    if (wv == 0) {
        unsigned cv[4];
        #pragma unroll
        for (int j = 0; j < 4; ++j) {
            const int idx = lane + 64 * j;
            const int w2 = idx / MAXC, i2 = idx % MAXC;
            cv[j] = (i2 < C) ? cbuf[w2 * MAXC + i2] : 0u;    // pad 0 never passes ct>=1
        }
        unsigned t = 0u;
        for (int bit = 31; bit >= 0; --bit) {
            const unsigned ct = t | (1u << bit);
            int cnt = 0;
            #pragma unroll
            for (int j = 0; j < 4; ++j)
                cnt += (int)__popcll(__ballot(cv[j] >= ct));
            if (cnt >= C) t = ct;
        }
        if (lane == 0) st = t;
    }
    __syncthreads();
    const unsigned t = st;

    // global recount: gt/eq packed scan in index order (wave shfl-scan + LDS combine)
    int gt = 0, eq = 0;
    #pragma unroll
    for (int j = 0; j < 8; ++j) { gt += (key[j] > t); eq += (key[j] == t); }
    const unsigned p = ((unsigned)gt << 16) | (unsigned)eq;
    unsigned x = p;
    #pragma unroll
    for (int off = 1; off < 64; off <<= 1) {
        const unsigned y = __shfl_up(x, off);
        if (lane >= off) x += y;
    }
    if (lane == 63) spack[wv] = x;   // wave inclusive total
    __syncthreads();
    unsigned base = 0, total = 0;
    #pragma unroll
    for (int w2 = 0; w2 < 4; ++w2) {
        const unsigned sv = spack[w2];
        total += sv;
        if (w2 < wv) base += sv;
    }
    const unsigned excl = base + x - p;             // exclusive prefix before my elements
    const int cgt_total = (int)(total >> 16);
    const int need      = C - cgt_total;            // >= 1 by maximality of t
    const int eq_before = (int)(excl & 0xFFFFu);

    // threshold value as exp offset: selected z - tval >= 0, bounded ~11; g <= 3 -> fp32-safe
    const float tval = __uint_as_float((t & 0x80000000u) ? (t ^ 0x80000000u) : ~t);
    const float g = gamma[b];
    const float tiny = __powf(1e-16f, g);           // may underflow to 0 — matches ref
    float a[8];
    float ssum = 0.f;
    int eqseen = 0;
    #pragma unroll
    for (int j = 0; j < 8; ++j) {
        const bool sel = (key[j] > t) || ((key[j] == t) && ((eq_before + eqseen) < need));
        eqseen += (key[j] == t);
        a[j] = __expf(g * (v[j] - tval)) * (sel ? 1.0f : tiny);
        ssum += a[j];
    }
    #pragma unroll
    for (int off = 32; off >= 1; off >>= 1) ssum += __shfl_xor(ssum, off);
    if (lane == 0) fred[wv] = ssum;
    __syncthreads();
    const float tot = (fred[0] + fred[1]) + (fred[2] + fred[3]);
    const float inv = 1.0f / tot;

    vf4 o0, o1;
    o0[0]=a[0]*inv; o0[1]=a[1]*inv; o0[2]=a[2]*inv; o0[3]=a[3]*inv;
    o1[0]=a[4]*inv; o1[1]=a[5]*inv; o1[2]=a[6]*inv; o1[3]=a[7]*inv;
    vf4* op = (vf4*)(out + (size_t)b * Nn) + (size_t)tid * 2;
    op[0] = o0;
    op[1] = o1;
}

extern "C" void kernel_launch(void* const* d_in, const int* in_sizes, int n_in,
                              void* d_out, int out_size, void* d_ws, size_t ws_size,
                              hipStream_t stream) {
    const float* q     = (const float*)d_in[0];   // k      [B,K]
    const float* beta  = (const float*)d_in[1];   // beta   [B,1]
    const float* gamma = (const float*)d_in[2];   // gamma  [B,1]
    const float* keys  = (const float*)d_in[3];   // keys   [B,N,K]
    const int*   cand  = (const int*)d_in[4];     // candidates (scalar)
    float* out = (float*)d_out;                   // w      [B,N]
    float* z   = (float*)d_ws;                    // scratch [B,N] floats = 1 MiB

    score_kernel<<<dim3(Bn * CHUNKS), dim3(TPB), 0, stream>>>(q, beta, keys, z);
    topk_kernel<<<dim3(Bn), dim3(TPB), 0, stream>>>(z, gamma, cand, out);
}